// Round 5
// baseline (195.734 us; speedup 1.0000x reference)
//
#include <hip/hip_runtime.h>
#include <hip/hip_bf16.h>

typedef __bf16 bf16x8 __attribute__((ext_vector_type(8)));
typedef float f32x4 __attribute__((ext_vector_type(4)));
typedef float f32x16 __attribute__((ext_vector_type(16)));

__device__ __forceinline__ ushort f2bf(float f) {
  union { float f; unsigned u; } x; x.f = f;
  unsigned r = x.u + 0x7fffu + ((x.u >> 16) & 1u);
  return (ushort)(r >> 16);
}

__device__ __forceinline__ void gld_lds16(const void* g, void* l) {
  __builtin_amdgcn_global_load_lds(
      (const __attribute__((address_space(1))) void*)g,
      (__attribute__((address_space(3))) void*)l, 16, 0, 0);
}

// ---------------- fused f32 -> bf16 convert (all 5 tensors, 1 launch) ------
__global__ __launch_bounds__(256) void k_cvt_all(
    const float* __restrict__ q, const float* __restrict__ k,
    const float* __restrict__ v, const float* __restrict__ wi,
    const float* __restrict__ wo, ushort* __restrict__ dst) {
  const int NQ = 1048576;            // float4s per q/k/v
  const int NWI = 196608, NWO = 65536;
  const int total = 3 * NQ + NWI + NWO;
  int i = blockIdx.x * 256 + threadIdx.x;
  int stride = gridDim.x * 256;
  for (; i < total; i += stride) {
    const float* s; int j;
    if (i < NQ)              { s = q;  j = i; }
    else if (i < 2 * NQ)     { s = k;  j = i - NQ; }
    else if (i < 3 * NQ)     { s = v;  j = i - 2 * NQ; }
    else if (i < 3 * NQ + NWI) { s = wi; j = i - 3 * NQ; }
    else                     { s = wo; j = i - 3 * NQ - NWI; }
    float4 val = reinterpret_cast<const float4*>(s)[j];
    ushort4 o;
    o.x = f2bf(val.x); o.y = f2bf(val.y); o.z = f2bf(val.z); o.w = f2bf(val.w);
    reinterpret_cast<ushort4*>(dst)[i] = o;
  }
}

// ---------------- bf16 GEMM  C = A @ Bt^T + bias  (optional z0 scale) ------
#define GK 512
#define GN 512

__global__ __launch_bounds__(256) void k_gemm(
    const ushort* __restrict__ Abase, size_t az,
    const ushort* __restrict__ Btbase, size_t bz,
    const float* __restrict__ biasbase, int biz,
    void* __restrict__ Cbase, size_t cz,
    int out_bf16, float qs)
{
  int z = blockIdx.z;
  const ushort* A  = Abase  + az * z;
  const ushort* Bt = Btbase + bz * z;
  const float* bias = biasbase + (size_t)biz * z;
  float osc = (z == 0) ? qs : 1.0f;

  __shared__ ushort As[128 * 32];
  __shared__ ushort Bs[128 * 32];

  int tid = threadIdx.x;
  int wv = tid >> 6, ln = tid & 63;
  int l15 = ln & 15, lg = ln >> 4;
  int wm = wv >> 1, wn = wv & 1;
  int m0 = blockIdx.x * 128, n0 = blockIdx.y * 128;

  f32x4 acc[4][4] = {};

  for (int kt = 0; kt < GK / 32; ++kt) {
    __syncthreads();
#pragma unroll
    for (int h2 = 0; h2 < 2; ++h2) {
      int c = h2 * 256 + wv * 64 + ln;
      int row = c >> 2, kc = (c & 3) * 8;
      gld_lds16(A  + (size_t)(m0 + row) * GK + kt * 32 + kc,
                (char*)As + (h2 * 256 + wv * 64) * 16);
      gld_lds16(Bt + (size_t)(n0 + row) * GK + kt * 32 + kc,
                (char*)Bs + (h2 * 256 + wv * 64) * 16);
    }
    __syncthreads();
    bf16x8 af[4], bf[4];
#pragma unroll
    for (int mf = 0; mf < 4; ++mf)
      af[mf] = *reinterpret_cast<const bf16x8*>(&As[(wm * 64 + mf * 16 + l15) * 32 + lg * 8]);
#pragma unroll
    for (int nf = 0; nf < 4; ++nf)
      bf[nf] = *reinterpret_cast<const bf16x8*>(&Bs[(wn * 64 + nf * 16 + l15) * 32 + lg * 8]);
#pragma unroll
    for (int mf = 0; mf < 4; ++mf)
#pragma unroll
      for (int nf = 0; nf < 4; ++nf)
        acc[mf][nf] = __builtin_amdgcn_mfma_f32_16x16x32_bf16(af[mf], bf[nf], acc[mf][nf], 0, 0, 0);
  }

#pragma unroll
  for (int mf = 0; mf < 4; ++mf)
#pragma unroll
    for (int nf = 0; nf < 4; ++nf)
#pragma unroll
      for (int r = 0; r < 4; ++r) {
        int rr = m0 + wm * 64 + mf * 16 + lg * 4 + r;
        int cc = n0 + wn * 64 + nf * 16 + l15;
        float v = (acc[mf][nf][r] + bias[cc]) * osc;
        if (out_bf16)
          ((ushort*)Cbase + cz * z)[(size_t)rr * GN + cc] = f2bf(v);
        else
          ((float*)Cbase)[(size_t)rr * GN + cc] = v;
      }
}

// ---------------- sliding-window attention v4 (pipelined) ----------------
// v3 structure (swapped-QK, in-reg softmax, permlane pack) + software
// pipeline: K-frags double-buffered in registers (kb+1 loads issued at
// iter start -> counted vmcnt), V ds_reads hoisted above exp/pack, asm
// non-volatile so the scheduler can interleave, psum tree-reduced.
__global__ __launch_bounds__(512, 4) void k_attn(
    const ushort* __restrict__ qp, const ushort* __restrict__ kp,
    const ushort* __restrict__ vp, ushort* __restrict__ ctx)
{
  const int E = 512, SEQ = 4096;
  int bid = blockIdx.x;
  int qh = bid & 1;
  int h = (bid >> 1) & 7;
  int n = (bid >> 4) % 15;
  int b = bid / 240;
  int start = n * 256;

  int tid = threadIdx.x;
  int w = tid >> 6, ln = tid & 63;
  int l31 = ln & 31, hi = ln >> 5;

  size_t base = ((size_t)(b * SEQ + start)) * E + h * 64;
  const ushort* Kw = kp + base;
  const ushort* Vw = vp + base;
  const ushort* Qw = qp + base;

  __shared__ ushort Vt[32768];  // Vt[d][k], 64KB, byte ^= (d&7)<<4

  // ---- stage V transposed: thread t owns global V row k=t ----
  {
    const ushort* src = Vw + (size_t)tid * E;
    uint4 rowv[8];
#pragma unroll
    for (int i = 0; i < 8; ++i)
      rowv[i] = reinterpret_cast<const uint4*>(src)[i];
    const uint* rw = (const uint*)rowv;
    char* lbw = (char*)Vt;
    int kb2 = tid * 2;
#pragma unroll
    for (int d = 0; d < 64; ++d) {
      uint vv = rw[d >> 1];
      ushort e = (d & 1) ? (ushort)(vv >> 16) : (ushort)(vv & 0xffffu);
      int off = d * 1024 + (kb2 ^ ((d & 7) << 4));
      *(ushort*)(lbw + off) = e;
    }
  }
  __syncthreads();

  int q0 = qh * 256 + w * 32;

  // Q B-frags: lane l holds Q[q0 + (l&31)][d = i*16 + hi*8 + j]
  bf16x8 qf[4];
#pragma unroll
  for (int i = 0; i < 4; ++i)
    qf[i] = *reinterpret_cast<const bf16x8*>(
        Qw + (size_t)(q0 + l31) * E + i * 16 + hi * 8);

  f32x16 c0 = {}, c1 = {};
  float psum = 0.f;
  const char* lb = (const char*)Vt;

  // K A-frag double buffer; preload kb=0
  bf16x8 kf[2][4];
#pragma unroll
  for (int i = 0; i < 4; ++i)
    kf[0][i] = *reinterpret_cast<const bf16x8*>(
        Kw + (size_t)l31 * E + i * 16 + hi * 8);

#pragma unroll
  for (int kb = 0; kb < 16; ++kb) {
    const int cur = kb & 1, nxt = cur ^ 1;

    // prefetch next K tile (in flight across this whole iteration)
    if (kb < 15) {
#pragma unroll
      for (int i = 0; i < 4; ++i)
        kf[nxt][i] = *reinterpret_cast<const bf16x8*>(
            Kw + (size_t)((kb + 1) * 32 + l31) * E + i * 16 + hi * 8);
    }

    // V B-frags for THIS iter (LDS; latency hides under exp/pack below)
    bf16x8 vb00, vb01, vb10, vb11;
    {
      int row = l31, rowh = 32 + l31;
      int cb0 = kb * 64 + hi * 16;
      int cb1 = cb0 + 32;
      vb00 = *reinterpret_cast<const bf16x8*>(lb + row * 1024 + (cb0 ^ ((row & 7) << 4)));
      vb01 = *reinterpret_cast<const bf16x8*>(lb + rowh * 1024 + (cb0 ^ ((row & 7) << 4)));
      vb10 = *reinterpret_cast<const bf16x8*>(lb + row * 1024 + (cb1 ^ ((row & 7) << 4)));
      vb11 = *reinterpret_cast<const bf16x8*>(lb + rowh * 1024 + (cb1 ^ ((row & 7) << 4)));
    }

    f32x16 s = {};
    __builtin_amdgcn_s_setprio(1);
#pragma unroll
    for (int i = 0; i < 4; ++i)
      s = __builtin_amdgcn_mfma_f32_32x32x16_bf16(kf[cur][i], qf[i], s, 0, 0, 0);
    __builtin_amdgcn_s_setprio(0);

    // exp (Q prescaled by 0.125*log2e) + tree partial sum
#pragma unroll
    for (int r = 0; r < 16; ++r)
      s[r] = __builtin_amdgcn_exp2f(s[r]);
    {
      float t0 = (s[0] + s[1]) + (s[2] + s[3]);
      float t1 = (s[4] + s[5]) + (s[6] + s[7]);
      float t2 = (s[8] + s[9]) + (s[10] + s[11]);
      float t3 = (s[12] + s[13]) + (s[14] + s[15]);
      psum += (t0 + t1) + (t2 + t3);
    }

    // pack P to bf16 words; build A-frags via permlane32_swap.
    // swap(a,b): a=[a.lo,b.lo], b=[a.hi,b.hi]; pair word i with i+2.
    uint cw[8];
#pragma unroll
    for (int i = 0; i < 8; ++i)
      asm("v_cvt_pk_bf16_f32 %0, %1, %2"
          : "=v"(cw[i]) : "v"(s[2 * i]), "v"(s[2 * i + 1]));
    asm("v_permlane32_swap_b32 %0, %1" : "+v"(cw[0]), "+v"(cw[2]));
    asm("v_permlane32_swap_b32 %0, %1" : "+v"(cw[1]), "+v"(cw[3]));
    asm("v_permlane32_swap_b32 %0, %1" : "+v"(cw[4]), "+v"(cw[6]));
    asm("v_permlane32_swap_b32 %0, %1" : "+v"(cw[5]), "+v"(cw[7]));
    union { uint u[4]; bf16x8 v; } A1, A2;
    A1.u[0] = cw[0]; A1.u[1] = cw[1]; A1.u[2] = cw[2]; A1.u[3] = cw[3];
    A2.u[0] = cw[4]; A2.u[1] = cw[5]; A2.u[2] = cw[6]; A2.u[3] = cw[7];

    __builtin_amdgcn_s_setprio(1);
    c0 = __builtin_amdgcn_mfma_f32_32x32x16_bf16(A1.v, vb00, c0, 0, 0, 0);
    c1 = __builtin_amdgcn_mfma_f32_32x32x16_bf16(A1.v, vb01, c1, 0, 0, 0);
    c0 = __builtin_amdgcn_mfma_f32_32x32x16_bf16(A2.v, vb10, c0, 0, 0, 0);
    c1 = __builtin_amdgcn_mfma_f32_32x32x16_bf16(A2.v, vb11, c1, 0, 0, 0);
    __builtin_amdgcn_s_setprio(0);
  }

  // combine halves (lane l and l+32 hold same q = l&31), normalize, store
  psum += __shfl_xor(psum, 32);
  float rinv_me = 1.0f / psum;
  size_t orow0 = (size_t)b * 7680 + (size_t)n * 512 + q0;
#pragma unroll
  for (int r = 0; r < 16; ++r) {
    int qrel = (r & 3) + 8 * (r >> 2) + 4 * hi;
    float ri = __shfl(rinv_me, qrel);
    ushort* dst = ctx + (orow0 + qrel) * E + h * 64 + l31;
    dst[0]  = f2bf(c0[r] * ri);
    dst[32] = f2bf(c1[r] * ri);
  }
}

// ---------------- launch ----------------
extern "C" void kernel_launch(void* const* d_in, const int* in_sizes, int n_in,
                              void* d_out, int out_size, void* d_ws, size_t ws_size,
                              hipStream_t stream) {
  const float* query = (const float*)d_in[0];
  const float* key   = (const float*)d_in[1];
  const float* value = (const float*)d_in[2];
  const float* ipw   = (const float*)d_in[3];
  const float* ipb   = (const float*)d_in[4];
  const float* opw   = (const float*)d_in[5];
  const float* opb   = (const float*)d_in[6];

  ushort* qb  = (ushort*)d_ws;
  ushort* kb  = qb  + 4194304;
  ushort* vb  = kb  + 4194304;
  ushort* wib = vb  + 4194304;
  ushort* wob = wib + 786432;
  ushort* qp  = wob + 262144;
  ushort* kp  = qp  + 4194304;
  ushort* vp  = kp  + 4194304;
  ushort* ctx = vp  + 4194304;

  const float SC = 0.125f * 1.44269504088896340736f;  // fold scale*log2e into Q

  k_cvt_all<<<2048, 256, 0, stream>>>(query, key, value, ipw, opw, qb);

  k_gemm<<<dim3(64, 4, 3), 256, 0, stream>>>(
      qb, (size_t)4194304, wib, (size_t)262144, ipb, 512,
      (void*)qp, (size_t)4194304, 1, SC);

  k_attn<<<480, 512, 0, stream>>>(qp, kp, vp, ctx);

  k_gemm<<<dim3(120, 4, 1), 256, 0, stream>>>(
      ctx, (size_t)0, wob, (size_t)0, opb, 0,
      d_out, (size_t)0, 0, 1.0f);
}

// Round 6
// 95.813 us; speedup vs baseline: 2.0429x; 2.0429x over previous
//
#include <hip/hip_runtime.h>
#include <hip/hip_bf16.h>

typedef __bf16 bf16x8 __attribute__((ext_vector_type(8)));
typedef float f32x4 __attribute__((ext_vector_type(4)));
typedef float f32x16 __attribute__((ext_vector_type(16)));

__device__ __forceinline__ ushort f2bf(float f) {
  union { float f; unsigned u; } x; x.f = f;
  unsigned r = x.u + 0x7fffu + ((x.u >> 16) & 1u);
  return (ushort)(r >> 16);
}

__device__ __forceinline__ void gld_lds16(const void* g, void* l) {
  __builtin_amdgcn_global_load_lds(
      (const __attribute__((address_space(1))) void*)g,
      (__attribute__((address_space(3))) void*)l, 16, 0, 0);
}

// ---------------- fused f32 -> bf16 convert (all 5 tensors, 1 launch) ------
__global__ __launch_bounds__(256) void k_cvt_all(
    const float* __restrict__ q, const float* __restrict__ k,
    const float* __restrict__ v, const float* __restrict__ wi,
    const float* __restrict__ wo, ushort* __restrict__ dst) {
  const int NQ = 1048576;            // float4s per q/k/v
  const int NWI = 196608, NWO = 65536;
  const int total = 3 * NQ + NWI + NWO;
  int i = blockIdx.x * 256 + threadIdx.x;
  int stride = gridDim.x * 256;
  for (; i < total; i += stride) {
    const float* s; int j;
    if (i < NQ)              { s = q;  j = i; }
    else if (i < 2 * NQ)     { s = k;  j = i - NQ; }
    else if (i < 3 * NQ)     { s = v;  j = i - 2 * NQ; }
    else if (i < 3 * NQ + NWI) { s = wi; j = i - 3 * NQ; }
    else                     { s = wo; j = i - 3 * NQ - NWI; }
    float4 val = reinterpret_cast<const float4*>(s)[j];
    ushort4 o;
    o.x = f2bf(val.x); o.y = f2bf(val.y); o.z = f2bf(val.z); o.w = f2bf(val.w);
    reinterpret_cast<ushort4*>(dst)[i] = o;
  }
}

// ---------------- bf16 GEMM  C = A @ Bt^T + bias  (optional z0 scale) ------
#define GK 512
#define GN 512

__global__ __launch_bounds__(256) void k_gemm(
    const ushort* __restrict__ Abase, size_t az,
    const ushort* __restrict__ Btbase, size_t bz,
    const float* __restrict__ biasbase, int biz,
    void* __restrict__ Cbase, size_t cz,
    int out_bf16, float qs)
{
  int z = blockIdx.z;
  const ushort* A  = Abase  + az * z;
  const ushort* Bt = Btbase + bz * z;
  const float* bias = biasbase + (size_t)biz * z;
  float osc = (z == 0) ? qs : 1.0f;

  __shared__ ushort As[128 * 32];
  __shared__ ushort Bs[128 * 32];

  int tid = threadIdx.x;
  int wv = tid >> 6, ln = tid & 63;
  int l15 = ln & 15, lg = ln >> 4;
  int wm = wv >> 1, wn = wv & 1;
  int m0 = blockIdx.x * 128, n0 = blockIdx.y * 128;

  f32x4 acc[4][4] = {};

  for (int kt = 0; kt < GK / 32; ++kt) {
    __syncthreads();
#pragma unroll
    for (int h2 = 0; h2 < 2; ++h2) {
      int c = h2 * 256 + wv * 64 + ln;
      int row = c >> 2, kc = (c & 3) * 8;
      gld_lds16(A  + (size_t)(m0 + row) * GK + kt * 32 + kc,
                (char*)As + (h2 * 256 + wv * 64) * 16);
      gld_lds16(Bt + (size_t)(n0 + row) * GK + kt * 32 + kc,
                (char*)Bs + (h2 * 256 + wv * 64) * 16);
    }
    __syncthreads();
    bf16x8 af[4], bf[4];
#pragma unroll
    for (int mf = 0; mf < 4; ++mf)
      af[mf] = *reinterpret_cast<const bf16x8*>(&As[(wm * 64 + mf * 16 + l15) * 32 + lg * 8]);
#pragma unroll
    for (int nf = 0; nf < 4; ++nf)
      bf[nf] = *reinterpret_cast<const bf16x8*>(&Bs[(wn * 64 + nf * 16 + l15) * 32 + lg * 8]);
#pragma unroll
    for (int mf = 0; mf < 4; ++mf)
#pragma unroll
      for (int nf = 0; nf < 4; ++nf)
        acc[mf][nf] = __builtin_amdgcn_mfma_f32_16x16x32_bf16(af[mf], bf[nf], acc[mf][nf], 0, 0, 0);
  }

#pragma unroll
  for (int mf = 0; mf < 4; ++mf)
#pragma unroll
    for (int nf = 0; nf < 4; ++nf)
#pragma unroll
      for (int r = 0; r < 4; ++r) {
        int rr = m0 + wm * 64 + mf * 16 + lg * 4 + r;
        int cc = n0 + wn * 64 + nf * 16 + l15;
        float v = (acc[mf][nf][r] + bias[cc]) * osc;
        if (out_bf16)
          ((ushort*)Cbase + cz * z)[(size_t)rr * GN + cc] = f2bf(v);
        else
          ((float*)Cbase)[(size_t)rr * GN + cc] = v;
      }
}

// ---------------- sliding-window attention v5 (pipelined, static idx) ------
// v4 structure (swapped-QK, in-reg softmax, permlane pack) + K register
// double-buffer with NAMED buffers kfA/kfB and a 2-step macro body so every
// register index is compile-time (rule #20: runtime-indexed ext_vector
// arrays spill to scratch — that was R5's 10x HBM-traffic regression).
__global__ __launch_bounds__(512, 4) void k_attn(
    const ushort* __restrict__ qp, const ushort* __restrict__ kp,
    const ushort* __restrict__ vp, ushort* __restrict__ ctx)
{
  const int E = 512, SEQ = 4096;
  int bid = blockIdx.x;
  int qh = bid & 1;
  int h = (bid >> 1) & 7;
  int n = (bid >> 4) % 15;
  int b = bid / 240;
  int start = n * 256;

  int tid = threadIdx.x;
  int w = tid >> 6, ln = tid & 63;
  int l31 = ln & 31, hi = ln >> 5;

  size_t base = ((size_t)(b * SEQ + start)) * E + h * 64;
  const ushort* Kw = kp + base;
  const ushort* Vw = vp + base;
  const ushort* Qw = qp + base;

  __shared__ ushort Vt[32768];  // Vt[d][k], 64KB, byte ^= (d&7)<<4

  // ---- stage V transposed: thread t owns global V row k=t ----
  {
    const ushort* src = Vw + (size_t)tid * E;
    uint4 rowv[8];
#pragma unroll
    for (int i = 0; i < 8; ++i)
      rowv[i] = reinterpret_cast<const uint4*>(src)[i];
    const uint* rw = (const uint*)rowv;
    char* lbw = (char*)Vt;
    int kb2 = tid * 2;
#pragma unroll
    for (int d = 0; d < 64; ++d) {
      uint vv = rw[d >> 1];
      ushort e = (d & 1) ? (ushort)(vv >> 16) : (ushort)(vv & 0xffffu);
      int off = d * 1024 + (kb2 ^ ((d & 7) << 4));
      *(ushort*)(lbw + off) = e;
    }
  }
  __syncthreads();

  int q0 = qh * 256 + w * 32;

  // Q B-frags: lane l holds Q[q0 + (l&31)][d = i*16 + hi*8 + j]
  bf16x8 qf[4];
#pragma unroll
  for (int i = 0; i < 4; ++i)
    qf[i] = *reinterpret_cast<const bf16x8*>(
        Qw + (size_t)(q0 + l31) * E + i * 16 + hi * 8);

  f32x16 c0 = {}, c1 = {};
  float psum = 0.f;
  const char* lb = (const char*)Vt;

  // K A-frag double buffer (named, statically indexed); preload kb=0
  bf16x8 kfA0, kfA1, kfA2, kfA3, kfB0, kfB1, kfB2, kfB3;
  kfA0 = *reinterpret_cast<const bf16x8*>(Kw + (size_t)l31 * E + 0 * 16 + hi * 8);
  kfA1 = *reinterpret_cast<const bf16x8*>(Kw + (size_t)l31 * E + 1 * 16 + hi * 8);
  kfA2 = *reinterpret_cast<const bf16x8*>(Kw + (size_t)l31 * E + 2 * 16 + hi * 8);
  kfA3 = *reinterpret_cast<const bf16x8*>(Kw + (size_t)l31 * E + 3 * 16 + hi * 8);

#define ATTN_STEP(KB, CUR0, CUR1, CUR2, CUR3, NXT0, NXT1, NXT2, NXT3, DO_PF) \
  {                                                                          \
    if (DO_PF) {                                                             \
      const ushort* kr = Kw + (size_t)(((KB) + 1) * 32 + l31) * E + hi * 8;  \
      NXT0 = *reinterpret_cast<const bf16x8*>(kr + 0 * 16);                  \
      NXT1 = *reinterpret_cast<const bf16x8*>(kr + 1 * 16);                  \
      NXT2 = *reinterpret_cast<const bf16x8*>(kr + 2 * 16);                  \
      NXT3 = *reinterpret_cast<const bf16x8*>(kr + 3 * 16);                  \
    }                                                                        \
    bf16x8 vb00, vb01, vb10, vb11;                                           \
    {                                                                        \
      int row = l31, rowh = 32 + l31;                                        \
      int cb0 = (KB) * 64 + hi * 16;                                         \
      int cb1 = cb0 + 32;                                                    \
      vb00 = *reinterpret_cast<const bf16x8*>(lb + row * 1024 + (cb0 ^ ((row & 7) << 4)));  \
      vb01 = *reinterpret_cast<const bf16x8*>(lb + rowh * 1024 + (cb0 ^ ((row & 7) << 4))); \
      vb10 = *reinterpret_cast<const bf16x8*>(lb + row * 1024 + (cb1 ^ ((row & 7) << 4)));  \
      vb11 = *reinterpret_cast<const bf16x8*>(lb + rowh * 1024 + (cb1 ^ ((row & 7) << 4))); \
    }                                                                        \
    f32x16 s = {};                                                           \
    __builtin_amdgcn_s_setprio(1);                                           \
    s = __builtin_amdgcn_mfma_f32_32x32x16_bf16(CUR0, qf[0], s, 0, 0, 0);    \
    s = __builtin_amdgcn_mfma_f32_32x32x16_bf16(CUR1, qf[1], s, 0, 0, 0);    \
    s = __builtin_amdgcn_mfma_f32_32x32x16_bf16(CUR2, qf[2], s, 0, 0, 0);    \
    s = __builtin_amdgcn_mfma_f32_32x32x16_bf16(CUR3, qf[3], s, 0, 0, 0);    \
    __builtin_amdgcn_s_setprio(0);                                           \
    _Pragma("unroll")                                                        \
    for (int r = 0; r < 16; ++r)                                             \
      s[r] = __builtin_amdgcn_exp2f(s[r]);                                   \
    {                                                                        \
      float t0 = (s[0] + s[1]) + (s[2] + s[3]);                              \
      float t1 = (s[4] + s[5]) + (s[6] + s[7]);                              \
      float t2 = (s[8] + s[9]) + (s[10] + s[11]);                            \
      float t3 = (s[12] + s[13]) + (s[14] + s[15]);                          \
      psum += (t0 + t1) + (t2 + t3);                                         \
    }                                                                        \
    uint cw0, cw1, cw2, cw3, cw4, cw5, cw6, cw7;                             \
    asm("v_cvt_pk_bf16_f32 %0, %1, %2" : "=v"(cw0) : "v"(s[0]),  "v"(s[1])); \
    asm("v_cvt_pk_bf16_f32 %0, %1, %2" : "=v"(cw1) : "v"(s[2]),  "v"(s[3])); \
    asm("v_cvt_pk_bf16_f32 %0, %1, %2" : "=v"(cw2) : "v"(s[4]),  "v"(s[5])); \
    asm("v_cvt_pk_bf16_f32 %0, %1, %2" : "=v"(cw3) : "v"(s[6]),  "v"(s[7])); \
    asm("v_cvt_pk_bf16_f32 %0, %1, %2" : "=v"(cw4) : "v"(s[8]),  "v"(s[9])); \
    asm("v_cvt_pk_bf16_f32 %0, %1, %2" : "=v"(cw5) : "v"(s[10]), "v"(s[11]));\
    asm("v_cvt_pk_bf16_f32 %0, %1, %2" : "=v"(cw6) : "v"(s[12]), "v"(s[13]));\
    asm("v_cvt_pk_bf16_f32 %0, %1, %2" : "=v"(cw7) : "v"(s[14]), "v"(s[15]));\
    asm("v_permlane32_swap_b32 %0, %1" : "+v"(cw0), "+v"(cw2));              \
    asm("v_permlane32_swap_b32 %0, %1" : "+v"(cw1), "+v"(cw3));              \
    asm("v_permlane32_swap_b32 %0, %1" : "+v"(cw4), "+v"(cw6));              \
    asm("v_permlane32_swap_b32 %0, %1" : "+v"(cw5), "+v"(cw7));              \
    union { uint u[4]; bf16x8 v; } A1, A2;                                   \
    A1.u[0] = cw0; A1.u[1] = cw1; A1.u[2] = cw2; A1.u[3] = cw3;              \
    A2.u[0] = cw4; A2.u[1] = cw5; A2.u[2] = cw6; A2.u[3] = cw7;              \
    __builtin_amdgcn_s_setprio(1);                                           \
    c0 = __builtin_amdgcn_mfma_f32_32x32x16_bf16(A1.v, vb00, c0, 0, 0, 0);   \
    c1 = __builtin_amdgcn_mfma_f32_32x32x16_bf16(A1.v, vb01, c1, 0, 0, 0);   \
    c0 = __builtin_amdgcn_mfma_f32_32x32x16_bf16(A2.v, vb10, c0, 0, 0, 0);   \
    c1 = __builtin_amdgcn_mfma_f32_32x32x16_bf16(A2.v, vb11, c1, 0, 0, 0);   \
    __builtin_amdgcn_s_setprio(0);                                           \
  }

  for (int kb = 0; kb < 16; kb += 2) {
    ATTN_STEP(kb,     kfA0, kfA1, kfA2, kfA3, kfB0, kfB1, kfB2, kfB3, true);
    ATTN_STEP(kb + 1, kfB0, kfB1, kfB2, kfB3, kfA0, kfA1, kfA2, kfA3, (kb < 14));
  }
#undef ATTN_STEP

  // combine halves (lane l and l+32 hold same q = l&31), normalize, store
  psum += __shfl_xor(psum, 32);
  float rinv_me = 1.0f / psum;
  size_t orow0 = (size_t)b * 7680 + (size_t)n * 512 + q0;
#pragma unroll
  for (int r = 0; r < 16; ++r) {
    int qrel = (r & 3) + 8 * (r >> 2) + 4 * hi;
    float ri = __shfl(rinv_me, qrel);
    ushort* dst = ctx + (orow0 + qrel) * E + h * 64 + l31;
    dst[0]  = f2bf(c0[r] * ri);
    dst[32] = f2bf(c1[r] * ri);
  }
}

// ---------------- launch ----------------
extern "C" void kernel_launch(void* const* d_in, const int* in_sizes, int n_in,
                              void* d_out, int out_size, void* d_ws, size_t ws_size,
                              hipStream_t stream) {
  const float* query = (const float*)d_in[0];
  const float* key   = (const float*)d_in[1];
  const float* value = (const float*)d_in[2];
  const float* ipw   = (const float*)d_in[3];
  const float* ipb   = (const float*)d_in[4];
  const float* opw   = (const float*)d_in[5];
  const float* opb   = (const float*)d_in[6];

  ushort* qb  = (ushort*)d_ws;
  ushort* kb  = qb  + 4194304;
  ushort* vb  = kb  + 4194304;
  ushort* wib = vb  + 4194304;
  ushort* wob = wib + 786432;
  ushort* qp  = wob + 262144;
  ushort* kp  = qp  + 4194304;
  ushort* vp  = kp  + 4194304;
  ushort* ctx = vp  + 4194304;

  const float SC = 0.125f * 1.44269504088896340736f;  // fold scale*log2e into Q

  k_cvt_all<<<2048, 256, 0, stream>>>(query, key, value, ipw, opw, qb);

  k_gemm<<<dim3(64, 4, 3), 256, 0, stream>>>(
      qb, (size_t)4194304, wib, (size_t)262144, ipb, 512,
      (void*)qp, (size_t)4194304, 1, SC);

  k_attn<<<480, 512, 0, stream>>>(qp, kp, vp, ctx);

  k_gemm<<<dim3(120, 4, 1), 256, 0, stream>>>(
      ctx, (size_t)0, wob, (size_t)0, opb, 0,
      d_out, (size_t)0, 0, 1.0f);
}